// Round 8
// baseline (366.060 us; speedup 1.0000x reference)
//
#include <hip/hip_runtime.h>
#include <stdint.h>

#define NN   50000
#define INC  512
#define OUTC 128
#define NB   782      // ceil(50000/64) buckets of 64 nodes
#define CAP  4096     // per-bucket capacity (mean 2046, max ~2210)
#define NWG  256      // scatter workgroups
#define NFRAG 3125    // 50000/16 row-fragments (exact)

typedef unsigned int  uint;
typedef unsigned short u16;
typedef short bf16x8 __attribute__((ext_vector_type(8)));
typedef float f32x4  __attribute__((ext_vector_type(4)));
typedef u16   u16x8  __attribute__((ext_vector_type(8)));

__device__ __forceinline__ u16 f2bf(float f) {        // RNE f32->bf16 (scalar path)
  uint u = __float_as_uint(f);
  u += 0x7fffu + ((u >> 16) & 1u);
  return (u16)(u >> 16);
}
__device__ __forceinline__ float bflo(uint v) { return __uint_as_float(v << 16); }
__device__ __forceinline__ float bfhi(uint v) { return __uint_as_float(v & 0xffff0000u); }

// packed RNE f32x2 -> bf16x2 (one VALU op)
__device__ __forceinline__ uint pkbf(float lo, float hi) {
  uint r;
  asm("v_cvt_pk_bf16_f32 %0, %1, %2" : "=v"(r) : "v"(lo), "v"(hi));
  return r;
}
__device__ __forceinline__ bf16x8 pack8(float4 a, float4 b) {
  union { uint u[4]; bf16x8 v; } c;
  c.u[0] = pkbf(a.x, a.y); c.u[1] = pkbf(a.z, a.w);
  c.u[2] = pkbf(b.x, b.y); c.u[3] = pkbf(b.z, b.w);
  return c.v;
}

// async global->LDS 16B copy (linear, wave-uniform-base + lane*16)
__device__ __forceinline__ void gl_lds16(const void* g, void* l) {
  __builtin_amdgcn_global_load_lds(
      (const __attribute__((address_space(1))) uint*)g,
      (__attribute__((address_space(3))) uint*)l, 16, 0, 0);
}

// ---------------- bucketed edge binning ----------------
__global__ __launch_bounds__(256) void k_scatter_pairs(const int* __restrict__ src,
                                                       const int* __restrict__ dst, int E,
                                                       uint* __restrict__ bucket_cursor,
                                                       uint* __restrict__ pairs) {
  __shared__ uint hist[NB];
  __shared__ uint base[NB];
  __shared__ uint cur[NB];
  const int t = threadIdx.x;
  const int chunk = (E + NWG - 1) / NWG;
  const int e0 = blockIdx.x * chunk;
  const int e1 = min(e0 + chunk, E);

  for (int i = t; i < NB; i += 256) hist[i] = 0;
  __syncthreads();
  for (int e = e0 + t; e < e1; e += 256) {
    int b = dst[e] >> 6;
    atomicAdd(&hist[b], 1u);
  }
  __syncthreads();
  for (int i = t; i < NB; i += 256) {
    uint c = hist[i];
    base[i] = c ? atomicAdd(&bucket_cursor[i * 16], c) : 0u;
    cur[i] = 0;
  }
  __syncthreads();
  for (int e = e0 + t; e < e1; e += 256) {
    int d = dst[e];
    int b = d >> 6;
    uint r = atomicAdd(&cur[b], 1u);
    uint off = base[b] + r;
    if (off < CAP) pairs[(size_t)b * CAP + off] = (uint)src[e] | ((uint)(d & 63) << 16);
  }
}

// ---------------- per-bucket counting sort -> sorted CSR + rs_packed + dis ----------------
__global__ __launch_bounds__(256) void k_sort(const uint* __restrict__ bucket_cursor,
                                              const uint* __restrict__ pairs,
                                              uint* __restrict__ csr,        // [NB*CAP] src ids
                                              uint* __restrict__ rs_packed,  // [NN] local_start | cnt<<16
                                              float* __restrict__ dis) {
  __shared__ uint plist[CAP];   // 16 KB
  __shared__ uint slist[CAP];   // 16 KB
  __shared__ uint cnt[64], pfx[64], cur[64];
  const int b = blockIdx.x, t = threadIdx.x;
  uint n_e = bucket_cursor[b * 16]; if (n_e > CAP) n_e = CAP;

  if (t < 64) cnt[t] = 0;
  __syncthreads();
  for (uint e = t; e < n_e; e += 256) {
    uint v = pairs[(size_t)b * CAP + e];
    plist[e] = v;
    atomicAdd(&cnt[(v >> 16) & 63u], 1u);
  }
  __syncthreads();
  if (t == 0) {
    uint run = 0;
    for (int i = 0; i < 64; ++i) { pfx[i] = run; run += cnt[i]; }
  }
  __syncthreads();
  if (t < 64) {
    cur[t] = pfx[t];
    int n = b * 64 + t;
    if (n < NN) {
      rs_packed[n] = pfx[t] | (cnt[t] << 16);
      dis[n] = rsqrtf((float)cnt[t] + 1.0f);
    }
  }
  __syncthreads();
  for (uint e = t; e < n_e; e += 256) {
    uint v = plist[e];
    uint pos = atomicAdd(&cur[(v >> 16) & 63u], 1u);
    slist[pos] = v & 0xffffu;
  }
  __syncthreads();
  for (uint e = t; e < n_e; e += 256) csr[(size_t)b * CAP + e] = slist[e];
}

// ---------------- fused weight prep: transpose + bf16 + pre-swizzle ----------------
// Output layout (both): [4 chunks][128 rows][128 k] bf16, row stride 256 B,
// byte-in-chunk = (row*256 + k*2) ^ ((row&7)<<4).
__global__ __launch_bounds__(256) void k_prep(const float* __restrict__ We,   // [512][128]
                                              const float* __restrict__ Wd,   // [128][512]
                                              uint8_t* __restrict__ oE,
                                              uint8_t* __restrict__ oD) {
  __shared__ float t[4096];
  const int tid = threadIdx.x;
  if (blockIdx.x < 16) {
    const int k0 = blockIdx.x * 32;
#pragma unroll
    for (int r = 0; r < 16; ++r) {
      int e = r * 256 + tid;
      int kk = e >> 7, n = e & 127;
      t[kk * 128 + n] = We[(size_t)(k0 + kk) * 128 + n];
    }
    __syncthreads();
#pragma unroll
    for (int it = 0; it < 2; ++it) {
      int item = it * 256 + tid;
      int n = item & 127, kc = item >> 7;
      int kg = k0 + kc * 8;
      int q = kg >> 7, kin = kg & 127;
      u16x8 p;
#pragma unroll
      for (int j = 0; j < 8; ++j) p[j] = f2bf(t[(kc * 8 + j) * 128 + n]);
      *(u16x8*)(oE + q * 32768 + ((((uint)n * 256) + (uint)kin * 2) ^ (uint)((n & 7) << 4))) = p;
    }
  } else {
    const int n0 = (blockIdx.x - 16) * 32;
#pragma unroll
    for (int r = 0; r < 16; ++r) {
      int e = r * 256 + tid;
      int k = e >> 5, nl = e & 31;
      t[k * 32 + nl] = Wd[(size_t)k * 512 + n0 + nl];
    }
    __syncthreads();
#pragma unroll
    for (int it = 0; it < 2; ++it) {
      int item = it * 256 + tid;
      int nl = item & 31, kc = item >> 5;
      int n = n0 + nl;
      int c = n >> 7, nin = n & 127;
      u16x8 p;
#pragma unroll
      for (int j = 0; j < 8; ++j) p[j] = f2bf(t[(kc * 8 + j) * 32 + nl]);
      *(u16x8*)(oD + c * 32768 + ((((uint)nin * 256) + (uint)kc * 16) ^ (uint)((nin & 7) << 4))) = p;
    }
  }
}

// ---------------- GEMM1 (MFMA): xws = bf16( (x @ W_enc) * dis[row] ) ----------------
// 256 blocks x 8 waves; W_enc (128 KB) fully LDS-resident; x direct from global.
// Each wave owns 1-2 of the 3125 16-row fragments; no main-loop barriers.
__global__ __launch_bounds__(512, 2) void k_gemm1(const float* __restrict__ x,
                                                  const uint8_t* __restrict__ WtE,
                                                  const float* __restrict__ dis,
                                                  u16* __restrict__ xws) {
  __shared__ __align__(16) uint8_t WL[131072];
  const int tid = threadIdx.x, lane = tid & 63, wv = tid >> 6;
  const int lane15 = lane & 15, laneh = lane >> 4;

#pragma unroll
  for (int i = 0; i < 16; ++i)
    gl_lds16(WtE + tid * 16 + i * 8192, WL + tid * 16 + i * 8192);
  __syncthreads();   // drains DMA

  const int s = blockIdx.x * 8 + wv;
  const int f0 = (s * NFRAG) >> 11, f1 = ((s + 1) * NFRAG) >> 11;

  for (int f = f0; f < f1; ++f) {
    const float* xr = x + (size_t)(f * 16 + lane15) * INC + laneh * 8;
    bf16x8 a[16];
#pragma unroll
    for (int g = 0; g < 2; ++g) {          // 2 groups of 8 slices (VGPR control)
      float4 u[16];
#pragma unroll
      for (int sl = 0; sl < 8; ++sl) {
        u[sl * 2]     = *(const float4*)(xr + (g * 8 + sl) * 32);
        u[sl * 2 + 1] = *(const float4*)(xr + (g * 8 + sl) * 32 + 4);
      }
#pragma unroll
      for (int sl = 0; sl < 8; ++sl)
        a[g * 8 + sl] = pack8(u[sl * 2], u[sl * 2 + 1]);
    }

    f32x4 acc[8];
#pragma unroll
    for (int nf = 0; nf < 8; ++nf) acc[nf] = (f32x4){0.f, 0.f, 0.f, 0.f};

#pragma unroll
    for (int sl = 0; sl < 16; ++sl) {
      const uint kb = ((uint)(sl >> 2) << 15) + (uint)(sl & 3) * 64 + (uint)laneh * 16;
#pragma unroll
      for (int nf = 0; nf < 8; ++nf) {
        int n = nf * 16 + lane15;
        bf16x8 b = *(const bf16x8*)(WL + ((kb + (uint)n * 256) ^ (uint)((n & 7) << 4)));
        acc[nf] = __builtin_amdgcn_mfma_f32_16x16x32_bf16(a[sl], b, acc[nf], 0, 0, 0);
      }
    }

#pragma unroll
    for (int r = 0; r < 4; ++r) {
      int row = f * 16 + laneh * 4 + r;
      float dv = dis[row];
#pragma unroll
      for (int nf = 0; nf < 8; ++nf)
        xws[(size_t)row * 128 + nf * 16 + lane15] = f2bf(acc[nf][r] * dv);
    }
  }
}

// ---------------- aggregate: per-node register gather (2 nodes/block, unroll 8) ----------------
__global__ __launch_bounds__(128) void k_aggregate(const u16* __restrict__ xws,
                                                   const float* __restrict__ dis,
                                                   const uint* __restrict__ rs_packed,
                                                   const uint* __restrict__ csr,
                                                   const float* __restrict__ bias,
                                                   uint8_t* __restrict__ zsw) {
  const int i = blockIdx.x * 2 + (threadIdx.x >> 6);
  const int lane = threadIdx.x & 63;
  const uint v = rs_packed[i];
  const uint s0 = (uint)(i >> 6) * CAP + (v & 0xffffu);
  const uint s1 = s0 + (v >> 16);

  float a0 = 0.f, a1 = 0.f;
  uint j = s0;
  for (; j + 7 < s1; j += 8) {
    uint idx[8], vv[8];
#pragma unroll
    for (int t = 0; t < 8; ++t) idx[t] = csr[j + t];
#pragma unroll
    for (int t = 0; t < 8; ++t) vv[t] = *(const uint*)(xws + (size_t)idx[t] * 128 + lane * 2);
#pragma unroll
    for (int t = 0; t < 8; ++t) { a0 += bflo(vv[t]); a1 += bfhi(vv[t]); }
  }
  for (; j < s1; ++j) {
    uint vv = *(const uint*)(xws + (size_t)csr[j] * 128 + lane * 2);
    a0 += bflo(vv); a1 += bfhi(vv);
  }
  uint vs = *(const uint*)(xws + (size_t)i * 128 + lane * 2);
  float di = dis[i];
  float2 bb = *(const float2*)(bias + lane * 2);
  float z0 = fmaxf(di * (a0 + bflo(vs)) + bb.x, 0.f);
  float z1 = fmaxf(di * (a1 + bfhi(vs)) + bb.y, 0.f);
  uint pk = (uint)f2bf(z0) | ((uint)f2bf(z1) << 16);
  *(uint*)(zsw + ((((uint)i * 256) + (uint)lane * 4) ^ (uint)((i & 7) << 4))) = pk;
}

// ---------------- decode (MFMA): out = softmax(z @ W_dec) ----------------
// 256 blocks x 8 waves; W_dec (128 KB) fully LDS-resident; z direct from global
// (pre-swizzled rows -> in-line permutation only). No main-loop barriers.
__global__ __launch_bounds__(512, 2) void k_decode(const uint8_t* __restrict__ zsw,
                                                   const uint8_t* __restrict__ WtD,
                                                   float* __restrict__ out) {
  __shared__ __align__(16) uint8_t WL[131072];
  const int tid = threadIdx.x, lane = tid & 63, wv = tid >> 6;
  const int lane15 = lane & 15, laneh = lane >> 4;

#pragma unroll
  for (int i = 0; i < 16; ++i)
    gl_lds16(WtD + tid * 16 + i * 8192, WL + tid * 16 + i * 8192);
  __syncthreads();

  const int s = blockIdx.x * 8 + wv;
  const int f0 = (s * NFRAG) >> 11, f1 = ((s + 1) * NFRAG) >> 11;

  for (int f = f0; f < f1; ++f) {
    const int zr = f * 16 + lane15;
    const uint zsz = (uint)((zr & 7) << 4);
    bf16x8 a[4];
#pragma unroll
    for (int s2 = 0; s2 < 4; ++s2)
      a[s2] = *(const bf16x8*)(zsw + (((uint)zr * 256 + s2 * 64 + laneh * 16) ^ zsz));

    f32x4 acc[32];
#pragma unroll
    for (int nf = 0; nf < 32; ++nf) acc[nf] = (f32x4){0.f, 0.f, 0.f, 0.f};

#pragma unroll
    for (int nf = 0; nf < 32; ++nf) {
      int n = nf * 16 + lane15;
      uint nb = ((uint)(n >> 7) << 15) + (uint)(n & 127) * 256 + (uint)laneh * 16;
      uint nsw = (uint)((n & 7) << 4);
#pragma unroll
      for (int s2 = 0; s2 < 4; ++s2) {
        bf16x8 b = *(const bf16x8*)(WL + ((nb + s2 * 64) ^ nsw));
        acc[nf] = __builtin_amdgcn_mfma_f32_16x16x32_bf16(a[s2], b, acc[nf], 0, 0, 0);
      }
    }

    // softmax over 512 cols (row lives in one 16-lane group) + store
#pragma unroll
    for (int r = 0; r < 4; ++r) {
      float m = acc[0][r];
#pragma unroll
      for (int nf = 1; nf < 32; ++nf) m = fmaxf(m, acc[nf][r]);
      m = fmaxf(m, __shfl_xor(m, 1)); m = fmaxf(m, __shfl_xor(m, 2));
      m = fmaxf(m, __shfl_xor(m, 4)); m = fmaxf(m, __shfl_xor(m, 8));
      float sum = 0.f;
#pragma unroll
      for (int nf = 0; nf < 32; ++nf) { acc[nf][r] = __expf(acc[nf][r] - m); sum += acc[nf][r]; }
      sum += __shfl_xor(sum, 1); sum += __shfl_xor(sum, 2);
      sum += __shfl_xor(sum, 4); sum += __shfl_xor(sum, 8);
      float inv = 1.0f / sum;
      int row = f * 16 + laneh * 4 + r;
      float* op = out + (size_t)row * INC + lane15;
#pragma unroll
      for (int nf = 0; nf < 32; ++nf)
        op[nf * 16] = acc[nf][r] * inv;
    }
  }
}

// ---------------- launch ----------------
extern "C" void kernel_launch(void* const* d_in, const int* in_sizes, int n_in,
                              void* d_out, int out_size, void* d_ws, size_t ws_size,
                              hipStream_t stream) {
  const float* x     = (const float*)d_in[0];
  const int*   ei    = (const int*)d_in[1];
  const float* W_enc = (const float*)d_in[2];
  const float* b_enc = (const float*)d_in[3];
  const float* W_dec = (const float*)d_in[4];
  float* out = (float*)d_out;

  const int E = in_sizes[1] / 2;
  const int* esrc = ei;
  const int* edst = ei + E;

  uint8_t* ws = (uint8_t*)d_ws;
  uint*  bucket_cursor = (uint*)(ws);                   // 50 KB (782 x 64B-padded)
  uint*  pairs         = (uint*)(ws + 0x10000);         // 12.8 MB
  uint*  csr           = (uint*)(ws + 0xC80000);        // 12.8 MB
  uint*  rs_packed     = (uint*)(ws + 0x1900000);       // 200 KB
  float* dis           = (float*)(ws + 0x1940000);      // 200 KB
  uint8_t* WtE         = ws + 0x1980000;                // 128 KB
  uint8_t* WtD         = ws + 0x19A0000;                // 128 KB
  u16*   xws           = (u16*)(ws + 0x19C0000);        // 12.8 MB
  uint8_t* zsw         = ws + 0x2600000;                // 12.8 MB -> ends ~50 MB

  hipMemsetAsync(bucket_cursor, 0, NB * 64, stream);
  k_scatter_pairs<<<NWG, 256, 0, stream>>>(esrc, edst, E, bucket_cursor, pairs);
  k_sort         <<<NB, 256, 0, stream>>>(bucket_cursor, pairs, csr, rs_packed, dis);
  k_prep         <<<32, 256, 0, stream>>>(W_enc, W_dec, WtE, WtD);
  k_gemm1        <<<256, 512, 0, stream>>>(x, WtE, dis, xws);
  k_aggregate    <<<NN / 2, 128, 0, stream>>>(xws, dis, rs_packed, csr, b_enc, zsw);
  k_decode       <<<256, 512, 0, stream>>>(zsw, WtD, out);
}